// Round 19
// baseline (7455.648 us; speedup 1.0000x reference)
//
#include <hip/hip_runtime.h>

#define N_PTS 16384
#define ROWF  131        // 3 coords + 128 features
#define M_OUT 4096       // N / POOL
#define KNN   16
#define FPS_T 256        // fps threads: 4 waves, 1 wave/SIMD (512-VGPR budget)

typedef unsigned long long u64;
typedef float f32x2 __attribute__((ext_vector_type(2)));

// DPP cross-lane helpers (VALU pipe). Control constants proven r10-r18.
template <int CTRL, int ROW_MASK>
__device__ __forceinline__ float fmax_dpp(float v) {
  const int p = __builtin_amdgcn_update_dpp(__float_as_int(v), __float_as_int(v),
                                            CTRL, ROW_MASK, 0xf, false);
  return fmaxf(v, __int_as_float(p));
}
template <int CTRL, int ROW_MASK>
__device__ __forceinline__ unsigned umin_dpp(unsigned v) {
  const unsigned p = (unsigned)__builtin_amdgcn_update_dpp((int)v, (int)v,
                                            CTRL, ROW_MASK, 0xf, false);
  return v < p ? v : p;
}

// ---------------------------------------------------------------------------
// 1) Extract coords into packed float4 (x,y,z,0), original index order.
// ---------------------------------------------------------------------------
__global__ void prep_kernel(const float* __restrict__ x,
                            float4* __restrict__ coords4) {
  const int p = blockIdx.x * blockDim.x + threadIdx.x;
  if (p < N_PTS) {
    coords4[p] = make_float4(x[p * ROWF + 0], x[p * ROWF + 1],
                             x[p * ROWF + 2], 0.0f);
  }
}

// ---------------------------------------------------------------------------
// 2) FPS v17: 256 threads x 64 points, 1 wave/SIMD (waves_per_eu(1,1)).
//    r17(16wx16p) == r18(8wx32p) == 1.47us/step: per-SIMD issue was
//    CONSERVED in both -- never tested whether intra-SIMD wave serialization
//    (staggered barrier arrivals) is the floor. Here each wave owns a SIMD:
//    updates run fully parallel on 4 SIMDs, arrival spread ~0, block folds
//    are 2 DPP levels, 512-VGPR budget holds all 64 pts + md resident
//    (~200 regs; m08: no spill through 450).
//    Structure = r17: pk-pair update (bitwise == numpy mul/add chain, no
//    fma) -> max3 tree (64) -> 6-level f32 DPP wave fold -> lane63
//    s_wmax[par] -> b1 -> 2-level block fold (mm) -> scalar-uniform winner
//    test -> winner wave only: 64-elem descending scan (min j -> min orig
//    idx tid+(j<<8)) + 6-level u32-min DPP -> s_arg[par] -> b2 -> 2-level
//    u32 block fold -> uniform winner load. Parity buffers as r17.
//    Exact numpy argmax-first-index semantics; absmax 0 expected.
// ---------------------------------------------------------------------------
#define REP64R(F) F(63) F(62) F(61) F(60) F(59) F(58) F(57) F(56) \
                  F(55) F(54) F(53) F(52) F(51) F(50) F(49) F(48) \
                  F(47) F(46) F(45) F(44) F(43) F(42) F(41) F(40) \
                  F(39) F(38) F(37) F(36) F(35) F(34) F(33) F(32) \
                  F(31) F(30) F(29) F(28) F(27) F(26) F(25) F(24) \
                  F(23) F(22) F(21) F(20) F(19) F(18) F(17) F(16) \
                  F(15) F(14) F(13) F(12) F(11) F(10) F(9) F(8) \
                  F(7) F(6) F(5) F(4) F(3) F(2) F(1) F(0)
#define REPP(F) F(0,0,1)    F(1,2,3)    F(2,4,5)    F(3,6,7) \
                F(4,8,9)    F(5,10,11)  F(6,12,13)  F(7,14,15) \
                F(8,16,17)  F(9,18,19)  F(10,20,21) F(11,22,23) \
                F(12,24,25) F(13,26,27) F(14,28,29) F(15,30,31) \
                F(16,32,33) F(17,34,35) F(18,36,37) F(19,38,39) \
                F(20,40,41) F(21,42,43) F(22,44,45) F(23,46,47) \
                F(24,48,49) F(25,50,51) F(26,52,53) F(27,54,55) \
                F(28,56,57) F(29,58,59) F(30,60,61) F(31,62,63)

__global__
__attribute__((amdgpu_flat_work_group_size(FPS_T, FPS_T)))
__attribute__((amdgpu_waves_per_eu(1, 1)))
void fps_kernel(const float4* __restrict__ coords4, float* __restrict__ out) {
#pragma clang fp contract(off)
  __shared__ float    s_wmax[2][4];
  __shared__ unsigned s_arg[2][4];
  const int tid = threadIdx.x, lane = tid & 63, wid = tid >> 6;

#define FPS_DECL(t,a,b) f32x2 PX##t, PY##t, PZ##t; float md##a, md##b;
  REPP(FPS_DECL)
#undef FPS_DECL

#define FPS_INIT(t,a,b) {                                                  \
    const float4 va = coords4[(a << 8) + tid];                             \
    const float4 vb = coords4[(b << 8) + tid];                             \
    PX##t = (f32x2){va.x, vb.x};                                           \
    PY##t = (f32x2){va.y, vb.y};                                           \
    PZ##t = (f32x2){va.z, vb.z};                                           \
    md##a = __int_as_float(0x7f800000);                                    \
    md##b = __int_as_float(0x7f800000); }
  REPP(FPS_INIT)
#undef FPS_INIT

  if (lane == 63) { s_arg[0][wid] = 0xFFFFFFFFu; s_arg[1][wid] = 0xFFFFFFFFu; }

  const float4 q0 = coords4[0];
  float qx = q0.x, qy = q0.y, qz = q0.z;
  if (tid == 0) { out[0] = qx; out[1] = qy; out[2] = qz; }

  for (int s = 1; s < M_OUT; ++s) {
    const int par = s & 1;
    const f32x2 QX = {qx, qx}, QY = {qy, qy}, QZ = {qz, qz};

    // ---- update all 64 points (pk pairs; IEEE RTNE per half, no fma)
#define FPS_UPD(t,a,b) {                                                   \
    const f32x2 dx = PX##t - QX;                                           \
    const f32x2 dy = PY##t - QY;                                           \
    const f32x2 dz = PZ##t - QZ;                                           \
    const f32x2 xx = dx * dx;                                              \
    const f32x2 yy = dy * dy;                                              \
    const f32x2 zz = dz * dz;                                              \
    const f32x2 ss = xx + yy;                                              \
    const f32x2 d2 = ss + zz;                                              \
    md##a = fminf(md##a, d2.x);                                            \
    md##b = fminf(md##b, d2.y); }
    REPP(FPS_UPD)
#undef FPS_UPD

    // ---- lane max over 64 via max3-friendly tree (21x max3 + fold)
    const float g0  = fmaxf(fmaxf(md0,  md1),  md2);
    const float g1  = fmaxf(fmaxf(md3,  md4),  md5);
    const float g2  = fmaxf(fmaxf(md6,  md7),  md8);
    const float g3  = fmaxf(fmaxf(md9,  md10), md11);
    const float g4  = fmaxf(fmaxf(md12, md13), md14);
    const float g5  = fmaxf(fmaxf(md15, md16), md17);
    const float g6  = fmaxf(fmaxf(md18, md19), md20);
    const float g7  = fmaxf(fmaxf(md21, md22), md23);
    const float g8  = fmaxf(fmaxf(md24, md25), md26);
    const float g9  = fmaxf(fmaxf(md27, md28), md29);
    const float g10 = fmaxf(fmaxf(md30, md31), md32);
    const float g11 = fmaxf(fmaxf(md33, md34), md35);
    const float g12 = fmaxf(fmaxf(md36, md37), md38);
    const float g13 = fmaxf(fmaxf(md39, md40), md41);
    const float g14 = fmaxf(fmaxf(md42, md43), md44);
    const float g15 = fmaxf(fmaxf(md45, md46), md47);
    const float g16 = fmaxf(fmaxf(md48, md49), md50);
    const float g17 = fmaxf(fmaxf(md51, md52), md53);
    const float g18 = fmaxf(fmaxf(md54, md55), md56);
    const float g19 = fmaxf(fmaxf(md57, md58), md59);
    const float g20 = fmaxf(fmaxf(md60, md61), md62);
    const float h0 = fmaxf(fmaxf(g0,  g1),  g2);
    const float h1 = fmaxf(fmaxf(g3,  g4),  g5);
    const float h2 = fmaxf(fmaxf(g6,  g7),  g8);
    const float h3 = fmaxf(fmaxf(g9,  g10), g11);
    const float h4 = fmaxf(fmaxf(g12, g13), g14);
    const float h5 = fmaxf(fmaxf(g15, g16), g17);
    const float h6 = fmaxf(fmaxf(g18, g19), g20);
    const float k0 = fmaxf(fmaxf(h0, h1), h2);
    const float k1 = fmaxf(fmaxf(h3, h4), h5);
    const float k2 = fmaxf(h6, md63);
    const float m  = fmaxf(fmaxf(k0, k1), k2);

    // ---- wave max (f32) via DPP; lane 63 ends with full wave max
    float fm = m;
    fm = fmax_dpp<0xB1,  0xf>(fm);   // quad_perm [1,0,3,2]
    fm = fmax_dpp<0x4E,  0xf>(fm);   // quad_perm [2,3,0,1]
    fm = fmax_dpp<0x141, 0xf>(fm);   // row_half_mirror
    fm = fmax_dpp<0x140, 0xf>(fm);   // row_mirror
    fm = fmax_dpp<0x142, 0xa>(fm);   // row_bcast15 -> rows 1,3
    fm = fmax_dpp<0x143, 0xc>(fm);   // row_bcast31 -> rows 2,3

    if (lane == 63) s_wmax[par][wid] = fm;
    __syncthreads();                             // barrier 1

    // reset the arg buffer last read before the PREVIOUS b1 (race-free)
    if (lane == 63) s_arg[par ^ 1][wid] = 0xFFFFFFFFu;

    // block max of 4 wave maxes (f32, 2 DPP levels within each quad)
    float bm = s_wmax[par][lane & 3];
    bm = fmax_dpp<0xB1, 0xf>(bm);
    bm = fmax_dpp<0x4E, 0xf>(bm);                // all lanes: block max mm

    // ---- winner-only index resolution (scalar-uniform branch)
    const int mwb = __builtin_amdgcn_readlane(__float_as_int(fm), 63);
    const int mmb = __builtin_amdgcn_readfirstlane(__float_as_int(bm));
    if (mwb == mmb) {                            // uniform: ~1 wave enters
      const float mmv = __int_as_float(mmb);
      unsigned c = 0xFFFFu;
#define FPS_SCAN(j) c = (md##j == mmv) ? (unsigned)j : c;
      REP64R(FPS_SCAN)
#undef FPS_SCAN
      unsigned nic = (unsigned)tid + (c << 8);   // junk (>4M) if no match
      nic = umin_dpp<0xB1,  0xf>(nic);
      nic = umin_dpp<0x4E,  0xf>(nic);
      nic = umin_dpp<0x141, 0xf>(nic);
      nic = umin_dpp<0x140, 0xf>(nic);
      nic = umin_dpp<0x142, 0xa>(nic);
      nic = umin_dpp<0x143, 0xc>(nic);
      if (lane == 63) s_arg[par][wid] = nic;
    }
    __syncthreads();                             // barrier 2

    unsigned av = s_arg[par][lane & 3];
    av = umin_dpp<0xB1, 0xf>(av);
    av = umin_dpp<0x4E, 0xf>(av);                // all lanes: winner index

    const int oidx = (int)av;
    const float4 wpt = coords4[oidx];            // one uniform 16B load
    qx = wpt.x; qy = wpt.y; qz = wpt.z;
    if (tid == 0) {
      float* orow = out + (size_t)s * ROWF;
      orow[0] = qx; orow[1] = qy; orow[2] = qz;
    }
  }
}

// ---------------------------------------------------------------------------
// 3) KNN top-16 (ties -> lowest index) fused with feature max-pool.
//    One wave per query; query coords read from out rows (written by fps).
//    Packed u64 (d2_bits<<32 | idx) == lex (d2, idx).
// ---------------------------------------------------------------------------
__global__ __launch_bounds__(256)
void knn_pool_kernel(const float* __restrict__ x,
                     const float4* __restrict__ coords4,
                     float* __restrict__ out) {
  const int lane = threadIdx.x & 63;
  const int q = blockIdx.x * 4 + (threadIdx.x >> 6);

  const float qx = out[(size_t)q * ROWF + 0];
  const float qy = out[(size_t)q * ROWF + 1];
  const float qz = out[(size_t)q * ROWF + 2];

  u64 h[KNN];
#pragma unroll
  for (int k = 0; k < KNN; ++k) h[k] = ~0ULL;

  for (int c = lane; c < N_PTS; c += 64) {
    const float4 v = coords4[c];                 // coalesced 16B
    const float dx = v.x - qx, dy = v.y - qy, dz = v.z - qz;
    const float d2 = __fadd_rn(__fadd_rn(__fmul_rn(dx, dx), __fmul_rn(dy, dy)),
                               __fmul_rn(dz, dz));
    const u64 e = ((u64)__float_as_uint(d2) << 32) | (unsigned)c;
    if (e < h[KNN - 1]) {
#pragma unroll
      for (int k = KNN - 1; k >= 1; --k) {
        const u64 prev = h[k - 1];
        h[k] = (e < prev) ? prev : ((e < h[k]) ? e : h[k]);
      }
      h[0] = (e < h[0]) ? e : h[0];
    }
  }

  int nbr[KNN];
#pragma unroll
  for (int rr = 0; rr < KNN; ++rr) {
    u64 best = h[0];
#pragma unroll
    for (int off = 32; off; off >>= 1) {
      const u64 o = __shfl_xor(best, off);
      best = (o < best) ? o : best;
    }
    nbr[rr] = (int)(unsigned)(best & 0xffffffffULL);
    if (h[0] == best) {
#pragma unroll
      for (int k = 0; k < KNN - 1; ++k) h[k] = h[k + 1];
      h[KNN - 1] = ~0ULL;
    }
  }

  float a0 = __int_as_float(0xff800000), a1 = a0;
#pragma unroll
  for (int rr = 0; rr < KNN; ++rr) {
    const float* row = x + (size_t)nbr[rr] * ROWF + 3;
    a0 = fmaxf(a0, row[lane]);
    a1 = fmaxf(a1, row[lane + 64]);
  }
  float* orow = out + (size_t)q * ROWF + 3;
  orow[lane] = a0;
  orow[lane + 64] = a1;
}

extern "C" void kernel_launch(void* const* d_in, const int* in_sizes, int n_in,
                              void* d_out, int out_size, void* d_ws, size_t ws_size,
                              hipStream_t stream) {
  const float* x = (const float*)d_in[0];
  float* out = (float*)d_out;

  float4* coords4 = (float4*)d_ws;          // N float4 (256 KB)

  hipLaunchKernelGGL(prep_kernel, dim3(64), dim3(256), 0, stream, x, coords4);
  hipLaunchKernelGGL(fps_kernel, dim3(1), dim3(FPS_T), 0, stream, coords4, out);
  hipLaunchKernelGGL(knn_pool_kernel, dim3(M_OUT / 4), dim3(256), 0, stream,
                     x, coords4, out);
}

// Round 20
// 6182.848 us; speedup vs baseline: 1.2059x; 1.2059x over previous
//
#include <hip/hip_runtime.h>

#define N_PTS 16384
#define ROWF  131        // 3 coords + 128 features
#define M_OUT 4096       // N / POOL
#define KNN   16
#define FPS_T 512        // fps threads (8 waves, 2/SIMD -> 256-VGPR budget)

typedef unsigned long long u64;
typedef float f32x2 __attribute__((ext_vector_type(2)));

// DPP cross-lane helpers (VALU pipe). Control constants proven r10-r19.
template <int CTRL, int ROW_MASK>
__device__ __forceinline__ float fmax_dpp(float v) {
  const int p = __builtin_amdgcn_update_dpp(__float_as_int(v), __float_as_int(v),
                                            CTRL, ROW_MASK, 0xf, false);
  return fmaxf(v, __int_as_float(p));
}
template <int CTRL, int ROW_MASK>
__device__ __forceinline__ unsigned umin_dpp(unsigned v) {
  const unsigned p = (unsigned)__builtin_amdgcn_update_dpp((int)v, (int)v,
                                            CTRL, ROW_MASK, 0xf, false);
  return v < p ? v : p;
}

// ---------------------------------------------------------------------------
// 1) Extract coords into packed float4 (x,y,z,0), original index order.
// ---------------------------------------------------------------------------
__global__ void prep_kernel(const float* __restrict__ x,
                            float4* __restrict__ coords4) {
  const int p = blockIdx.x * blockDim.x + threadIdx.x;
  if (p < N_PTS) {
    coords4[p] = make_float4(x[p * ROWF + 0], x[p * ROWF + 1],
                             x[p * ROWF + 2], 0.0f);
  }
}

// ---------------------------------------------------------------------------
// 2) FPS v18 = r18 (best: 6008us, 8 waves x 32 pts, 2/SIMD) with the last
//    scalar min/max machinery packed. r19 falsified the serialization
//    theory (1 wave/SIMD: 7284us -- latency exposed); r15->r17 proved
//    instruction count is the live lever. Changes vs r18:
//    (a) md kept as f32x2 pairs; __builtin_elementwise_min -> v_pk_min_f32
//        (IEEE per-half == fminf bitwise; no NaNs: md starts +inf, d2
//        finite >=0). Update 10->9 instr/pair.
//    (b) lane max via pk_max tree (15 pk + 1 scalar vs ~31 scalar).
//    (c) winner-only scan reads pair halves, descending j (y before x
//        within pair, pairs descending) -> exact first-index ties.
//    (d) winner index readfirstlane'd -> scalar (SMEM-able) coords load.
//    Everything else byte-identical to r18 (f32 DPP folds, parity LDS,
//    2 barriers, winner-only resolution). absmax 0 expected.
// ---------------------------------------------------------------------------
#define REPP(F) F(0,0,1)   F(1,2,3)   F(2,4,5)   F(3,6,7) \
                F(4,8,9)   F(5,10,11) F(6,12,13) F(7,14,15) \
                F(8,16,17) F(9,18,19) F(10,20,21) F(11,22,23) \
                F(12,24,25) F(13,26,27) F(14,28,29) F(15,30,31)
#define REPPR(F) F(15,30,31) F(14,28,29) F(13,26,27) F(12,24,25) \
                 F(11,22,23) F(10,20,21) F(9,18,19)  F(8,16,17) \
                 F(7,14,15)  F(6,12,13)  F(5,10,11)  F(4,8,9) \
                 F(3,6,7)    F(2,4,5)    F(1,2,3)    F(0,0,1)

__global__
__attribute__((amdgpu_flat_work_group_size(FPS_T, FPS_T)))
__attribute__((amdgpu_waves_per_eu(2, 2)))
void fps_kernel(const float4* __restrict__ coords4, float* __restrict__ out) {
#pragma clang fp contract(off)
  __shared__ float    s_wmax[2][8];
  __shared__ unsigned s_arg[2][8];
  const int tid = threadIdx.x, lane = tid & 63, wid = tid >> 6;

#define FPS_DECL(t,a,b) f32x2 PX##t, PY##t, PZ##t, MD##t;
  REPP(FPS_DECL)
#undef FPS_DECL

#define FPS_INIT(t,a,b) {                                                  \
    const float4 va = coords4[(a << 9) + tid];                             \
    const float4 vb = coords4[(b << 9) + tid];                             \
    PX##t = (f32x2){va.x, vb.x};                                           \
    PY##t = (f32x2){va.y, vb.y};                                           \
    PZ##t = (f32x2){va.z, vb.z};                                           \
    MD##t = (f32x2){__int_as_float(0x7f800000),                            \
                    __int_as_float(0x7f800000)}; }
  REPP(FPS_INIT)
#undef FPS_INIT

  if (lane == 63) { s_arg[0][wid] = 0xFFFFFFFFu; s_arg[1][wid] = 0xFFFFFFFFu; }

  const float4 q0 = coords4[0];
  float qx = q0.x, qy = q0.y, qz = q0.z;
  if (tid == 0) { out[0] = qx; out[1] = qy; out[2] = qz; }

  for (int s = 1; s < M_OUT; ++s) {
    const int par = s & 1;
    const f32x2 QX = {qx, qx}, QY = {qy, qy}, QZ = {qz, qz};

    // ---- update all 32 points (fully packed: 9 pk instr / 2 points)
#define FPS_UPD(t,a,b) {                                                   \
    const f32x2 dx = PX##t - QX;                                           \
    const f32x2 dy = PY##t - QY;                                           \
    const f32x2 dz = PZ##t - QZ;                                           \
    const f32x2 xx = dx * dx;                                              \
    const f32x2 yy = dy * dy;                                              \
    const f32x2 zz = dz * dz;                                              \
    const f32x2 ss = xx + yy;                                              \
    const f32x2 d2 = ss + zz;                                              \
    MD##t = __builtin_elementwise_min(MD##t, d2); }
    REPP(FPS_UPD)
#undef FPS_UPD

    // ---- lane max via pk_max tree (15 pk + 1 scalar)
    const f32x2 t0 = __builtin_elementwise_max(MD0,  MD1);
    const f32x2 t1 = __builtin_elementwise_max(MD2,  MD3);
    const f32x2 t2 = __builtin_elementwise_max(MD4,  MD5);
    const f32x2 t3 = __builtin_elementwise_max(MD6,  MD7);
    const f32x2 t4 = __builtin_elementwise_max(MD8,  MD9);
    const f32x2 t5 = __builtin_elementwise_max(MD10, MD11);
    const f32x2 t6 = __builtin_elementwise_max(MD12, MD13);
    const f32x2 t7 = __builtin_elementwise_max(MD14, MD15);
    const f32x2 u0 = __builtin_elementwise_max(t0, t1);
    const f32x2 u1 = __builtin_elementwise_max(t2, t3);
    const f32x2 u2 = __builtin_elementwise_max(t4, t5);
    const f32x2 u3 = __builtin_elementwise_max(t6, t7);
    const f32x2 v0 = __builtin_elementwise_max(u0, u1);
    const f32x2 v1 = __builtin_elementwise_max(u2, u3);
    const f32x2 w0 = __builtin_elementwise_max(v0, v1);
    const float m  = fmaxf(w0.x, w0.y);

    // ---- wave max (f32) via DPP; lane 63 ends with full wave max
    float fm = m;
    fm = fmax_dpp<0xB1,  0xf>(fm);   // quad_perm [1,0,3,2]
    fm = fmax_dpp<0x4E,  0xf>(fm);   // quad_perm [2,3,0,1]
    fm = fmax_dpp<0x141, 0xf>(fm);   // row_half_mirror
    fm = fmax_dpp<0x140, 0xf>(fm);   // row_mirror
    fm = fmax_dpp<0x142, 0xa>(fm);   // row_bcast15 -> rows 1,3
    fm = fmax_dpp<0x143, 0xc>(fm);   // row_bcast31 -> rows 2,3

    if (lane == 63) s_wmax[par][wid] = fm;
    __syncthreads();                             // barrier 1

    // reset the arg buffer last read before the PREVIOUS b1 (race-free)
    if (lane == 63) s_arg[par ^ 1][wid] = 0xFFFFFFFFu;

    // block max of 8 wave maxes (f32, 3 DPP levels)
    float bm = s_wmax[par][lane & 7];
    bm = fmax_dpp<0xB1,  0xf>(bm);
    bm = fmax_dpp<0x4E,  0xf>(bm);
    bm = fmax_dpp<0x141, 0xf>(bm);               // all lanes: block max mm

    // ---- winner-only index resolution (scalar-uniform branch)
    const int mwb = __builtin_amdgcn_readlane(__float_as_int(fm), 63);
    const int mmb = __builtin_amdgcn_readfirstlane(__float_as_int(bm));
    if (mwb == mmb) {                            // uniform: ~1 wave enters
      const float mmv = __int_as_float(mmb);
      // descending j: pairs descending, y (odd, higher j) before x (even)
      unsigned c = 0xFFFFu;
#define FPS_SCAN(t,a,b) c = (MD##t.y == mmv) ? (unsigned)(b) : c;          \
                        c = (MD##t.x == mmv) ? (unsigned)(a) : c;
      REPPR(FPS_SCAN)
#undef FPS_SCAN
      unsigned nic = (unsigned)tid + (c << 9);   // junk (>33M) if no match
      nic = umin_dpp<0xB1,  0xf>(nic);
      nic = umin_dpp<0x4E,  0xf>(nic);
      nic = umin_dpp<0x141, 0xf>(nic);
      nic = umin_dpp<0x140, 0xf>(nic);
      nic = umin_dpp<0x142, 0xa>(nic);
      nic = umin_dpp<0x143, 0xc>(nic);
      if (lane == 63) s_arg[par][wid] = nic;
    }
    __syncthreads();                             // barrier 2

    unsigned av = s_arg[par][lane & 7];
    av = umin_dpp<0xB1,  0xf>(av);
    av = umin_dpp<0x4E,  0xf>(av);
    av = umin_dpp<0x141, 0xf>(av);               // all lanes: winner index

    // wave-uniform winner index -> scalar (SMEM-able) load path
    const int oidx = __builtin_amdgcn_readfirstlane((int)av);
    const float4 wpt = coords4[oidx];            // one uniform 16B load
    qx = wpt.x; qy = wpt.y; qz = wpt.z;
    if (tid == 0) {
      float* orow = out + (size_t)s * ROWF;
      orow[0] = qx; orow[1] = qy; orow[2] = qz;
    }
  }
}

// ---------------------------------------------------------------------------
// 3) KNN top-16 (ties -> lowest index) fused with feature max-pool.
//    One wave per query; query coords read from out rows (written by fps).
//    Packed u64 (d2_bits<<32 | idx) == lex (d2, idx).
// ---------------------------------------------------------------------------
__global__ __launch_bounds__(256)
void knn_pool_kernel(const float* __restrict__ x,
                     const float4* __restrict__ coords4,
                     float* __restrict__ out) {
  const int lane = threadIdx.x & 63;
  const int q = blockIdx.x * 4 + (threadIdx.x >> 6);

  const float qx = out[(size_t)q * ROWF + 0];
  const float qy = out[(size_t)q * ROWF + 1];
  const float qz = out[(size_t)q * ROWF + 2];

  u64 h[KNN];
#pragma unroll
  for (int k = 0; k < KNN; ++k) h[k] = ~0ULL;

  for (int c = lane; c < N_PTS; c += 64) {
    const float4 v = coords4[c];                 // coalesced 16B
    const float dx = v.x - qx, dy = v.y - qy, dz = v.z - qz;
    const float d2 = __fadd_rn(__fadd_rn(__fmul_rn(dx, dx), __fmul_rn(dy, dy)),
                               __fmul_rn(dz, dz));
    const u64 e = ((u64)__float_as_uint(d2) << 32) | (unsigned)c;
    if (e < h[KNN - 1]) {
#pragma unroll
      for (int k = KNN - 1; k >= 1; --k) {
        const u64 prev = h[k - 1];
        h[k] = (e < prev) ? prev : ((e < h[k]) ? e : h[k]);
      }
      h[0] = (e < h[0]) ? e : h[0];
    }
  }

  int nbr[KNN];
#pragma unroll
  for (int rr = 0; rr < KNN; ++rr) {
    u64 best = h[0];
#pragma unroll
    for (int off = 32; off; off >>= 1) {
      const u64 o = __shfl_xor(best, off);
      best = (o < best) ? o : best;
    }
    nbr[rr] = (int)(unsigned)(best & 0xffffffffULL);
    if (h[0] == best) {
#pragma unroll
      for (int k = 0; k < KNN - 1; ++k) h[k] = h[k + 1];
      h[KNN - 1] = ~0ULL;
    }
  }

  float a0 = __int_as_float(0xff800000), a1 = a0;
#pragma unroll
  for (int rr = 0; rr < KNN; ++rr) {
    const float* row = x + (size_t)nbr[rr] * ROWF + 3;
    a0 = fmaxf(a0, row[lane]);
    a1 = fmaxf(a1, row[lane + 64]);
  }
  float* orow = out + (size_t)q * ROWF + 3;
  orow[lane] = a0;
  orow[lane + 64] = a1;
}

extern "C" void kernel_launch(void* const* d_in, const int* in_sizes, int n_in,
                              void* d_out, int out_size, void* d_ws, size_t ws_size,
                              hipStream_t stream) {
  const float* x = (const float*)d_in[0];
  float* out = (float*)d_out;

  float4* coords4 = (float4*)d_ws;          // N float4 (256 KB)

  hipLaunchKernelGGL(prep_kernel, dim3(64), dim3(256), 0, stream, x, coords4);
  hipLaunchKernelGGL(fps_kernel, dim3(1), dim3(FPS_T), 0, stream, coords4, out);
  hipLaunchKernelGGL(knn_pool_kernel, dim3(M_OUT / 4), dim3(256), 0, stream,
                     x, coords4, out);
}